// Round 3
// baseline (402.712 us; speedup 1.0000x reference)
//
#include <hip/hip_runtime.h>
#include <stdint.h>

// Problem constants (B=8, K=4, N=131072)
#define NPER      131072      // N = 2^17
#define NTOT      4194304LL   // B*K*N
#define CHUNK     2048        // elements per block
#define NBLK      2048        // NTOT / CHUNK
#define NEG_PAD   (-1000.0f)
#define NEG_IDLE  (-100000000.0f)

typedef unsigned long long u64;

// flag word: bits[0:24) = inclusive/aggregate surface count
//            bits[24:48) = inclusive/aggregate air count
//            bits[62:64) = 0 invalid / 1 aggregate / 2 prefix
__device__ __forceinline__ u64 ld_acq(const u64* p) {
    return __hip_atomic_load(p, __ATOMIC_ACQUIRE, __HIP_MEMORY_SCOPE_AGENT);
}
__device__ __forceinline__ void st_rel(u64* p, u64 v) {
    __hip_atomic_store(p, v, __ATOMIC_RELEASE, __HIP_MEMORY_SCOPE_AGENT);
}

__global__ __launch_bounds__(256, 4) void fused_expand(
    const float* __restrict__ rgb, const float* __restrict__ lsurf,
    const float* __restrict__ lair, const float* __restrict__ idle,
    const int* __restrict__ ms, const int* __restrict__ ma,
    unsigned rgb_max, unsigned ts_max, unsigned ta_max,
    unsigned* __restrict__ ticket, u64* __restrict__ flags,
    float* __restrict__ out_rgb, float* __restrict__ out_ls, float* __restrict__ out_la)
{
    __shared__ unsigned sh_bid;
    __shared__ unsigned wsum[4];
    __shared__ unsigned sh_exc[2];
    const int t = threadIdx.x, lane = t & 63, wave = t >> 6;

    // Dynamic block id: guarantees all lookback predecessors already started.
    if (t == 0) sh_bid = atomicAdd(ticket, 1u);
    __syncthreads();
    const unsigned bid = sh_bid;
    const long long base = (long long)bid * CHUNK;

    // ---- load masks ONCE (int32 bools), compress to 8-bit fields ----
    const int4* ms4 = (const int4*)(ms + base);
    const int4* ma4 = (const int4*)(ma + base);
    int4 s0 = ms4[2 * t], s1 = ms4[2 * t + 1];
    int4 a0 = ma4[2 * t], a1 = ma4[2 * t + 1];
    unsigned sbits = (unsigned)(s0.x != 0)        | ((unsigned)(s0.y != 0) << 1)
                   | ((unsigned)(s0.z != 0) << 2) | ((unsigned)(s0.w != 0) << 3)
                   | ((unsigned)(s1.x != 0) << 4) | ((unsigned)(s1.y != 0) << 5)
                   | ((unsigned)(s1.z != 0) << 6) | ((unsigned)(s1.w != 0) << 7);
    unsigned abits = (unsigned)(a0.x != 0)        | ((unsigned)(a0.y != 0) << 1)
                   | ((unsigned)(a0.z != 0) << 2) | ((unsigned)(a0.w != 0) << 3)
                   | ((unsigned)(a1.x != 0) << 4) | ((unsigned)(a1.y != 0) << 5)
                   | ((unsigned)(a1.z != 0) << 6) | ((unsigned)(a1.w != 0) << 7);
    unsigned cs = __popc(sbits), ca = __popc(abits);

    // ---- single block scan over per-thread counts (packed s | a<<16) ----
    unsigned cnt = cs | (ca << 16);
    unsigned x = cnt;
    #pragma unroll
    for (int o = 1; o < 64; o <<= 1) {
        unsigned y = __shfl_up(x, o, 64);
        if (lane >= o) x += y;
    }
    if (lane == 63) wsum[wave] = x;
    __syncthreads();
    unsigned w0 = wsum[0], w1 = wsum[1], w2 = wsum[2], w3 = wsum[3];
    unsigned pre   = (wave > 0 ? w0 : 0u) + (wave > 1 ? w1 : 0u) + (wave > 2 ? w2 : 0u);
    unsigned tExcl = pre + x - cnt;                 // packed per-thread exclusive
    unsigned tot   = w0 + w1 + w2 + w3;
    unsigned totS  = tot & 0xffffu, totA = tot >> 16;

    // ---- decoupled lookback ----
    if (bid == 0) {
        if (t == 0) {
            st_rel(&flags[0], (u64)totS | ((u64)totA << 24) | (2ULL << 62));
            sh_exc[0] = 0u; sh_exc[1] = 0u;
        }
    } else {
        if (t == 0)   // publish aggregate ASAP
            st_rel(&flags[bid], (u64)totS | ((u64)totA << 24) | (1ULL << 62));
        if (wave == 0) {
            unsigned accS = 0, accA = 0, off = 0;
            for (;;) {
                int idx = (int)bid - 1 - (int)off - lane;
                u64 w = (idx >= 0) ? ld_acq(&flags[idx]) : (2ULL << 62);
                int fl = (int)(w >> 62);
                u64 validm = __ballot(fl != 0);
                u64 prefm  = __ballot(fl == 2);
                unsigned vs = (unsigned)(w & 0xffffffu);
                unsigned va = (unsigned)((w >> 24) & 0xffffffu);
                if (prefm) {
                    int p = __ffsll(prefm) - 1;          // closest predecessor with PREFIX
                    u64 need = (p >= 63) ? ~0ULL : ((1ULL << (p + 1)) - 1ULL);
                    if ((validm & need) == need) {
                        if (lane > p) { vs = 0; va = 0; }
                        #pragma unroll
                        for (int o = 32; o; o >>= 1) {
                            vs += __shfl_down(vs, o, 64);
                            va += __shfl_down(va, o, 64);
                        }
                        accS += __shfl(vs, 0, 64);
                        accA += __shfl(va, 0, 64);
                        break;
                    }
                } else if (~validm == 0ULL) {            // full window of aggregates
                    #pragma unroll
                    for (int o = 32; o; o >>= 1) {
                        vs += __shfl_down(vs, o, 64);
                        va += __shfl_down(va, o, 64);
                    }
                    accS += __shfl(vs, 0, 64);
                    accA += __shfl(va, 0, 64);
                    off += 64;
                }
                __builtin_amdgcn_s_sleep(1);
            }
            if (lane == 0) {
                st_rel(&flags[bid],
                       (u64)(accS + totS) | ((u64)(accA + totA) << 24) | (2ULL << 62));
                sh_exc[0] = accS; sh_exc[1] = accA;
            }
        }
    }
    __syncthreads();
    const unsigned excS = sh_exc[0], excA = sh_exc[1];

    // ---- expand + write: each thread owns 8 consecutive elements ----
    const int bk = (int)(base >> 17);                // chunk lies in one (b,k) row
    const float idle_v    = idle[bk];
    const float alive     = 1.0f - idle_v;
    const float idle_term = idle_v * NEG_IDLE;

    unsigned rs = excS + (tExcl & 0xffffu);
    unsigned ra = excA + (tExcl >> 16);
    const long long e0 = base + 8LL * t;

    float ls_b[8]  __attribute__((aligned(16)));
    float la_b[8]  __attribute__((aligned(16)));
    float rg_b[24] __attribute__((aligned(16)));
    #pragma unroll
    for (int j = 0; j < 8; ++j) {
        if ((sbits >> j) & 1u) {
            unsigned pr = rs < rgb_max ? rs : rgb_max;   // _expand's clip
            long long q = 3LL * pr;
            rg_b[3 * j]     = rgb[q]     * alive;
            rg_b[3 * j + 1] = rgb[q + 1] * alive;
            rg_b[3 * j + 2] = rgb[q + 2] * alive;
            unsigned pl = rs < ts_max ? rs : ts_max;
            ls_b[j] = lsurf[pl] * alive + idle_term;
            rs++;
        } else {
            rg_b[3 * j] = 0.f; rg_b[3 * j + 1] = 0.f; rg_b[3 * j + 2] = 0.f;
            ls_b[j] = NEG_PAD;
        }
        if ((abits >> j) & 1u) {
            unsigned pa = ra < ta_max ? ra : ta_max;
            la_b[j] = lair[pa] * alive + idle_term;
            ra++;
        } else {
            la_b[j] = NEG_PAD;
        }
    }

    float4* ols = (float4*)(out_ls + e0);
    ols[0] = ((float4*)ls_b)[0]; ols[1] = ((float4*)ls_b)[1];
    float4* ola = (float4*)(out_la + e0);
    ola[0] = ((float4*)la_b)[0]; ola[1] = ((float4*)la_b)[1];
    float4* org = (float4*)(out_rgb + 3 * e0);
    #pragma unroll
    for (int q = 0; q < 6; ++q) org[q] = ((float4*)rg_b)[q];
}

extern "C" void kernel_launch(void* const* d_in, const int* in_sizes, int n_in,
                              void* d_out, int out_size, void* d_ws, size_t ws_size,
                              hipStream_t stream)
{
    const float* rgb   = (const float*)d_in[0];
    const float* lsurf = (const float*)d_in[1];
    const float* lair  = (const float*)d_in[2];
    const float* idle  = (const float*)d_in[3];
    const int*   ms    = (const int*)d_in[4];   // bool -> int32 per harness contract
    const int*   ma    = (const int*)d_in[5];

    unsigned rgb_max = (unsigned)(in_sizes[0] / 3 - 1);
    unsigned ts_max  = (unsigned)(in_sizes[1] - 1);
    unsigned ta_max  = (unsigned)(in_sizes[2] - 1);

    float* out     = (float*)d_out;
    float* out_rgb = out;                  // (B,K,N,3)
    float* out_ls  = out + NTOT * 3;       // (B,K,N,1)
    float* out_la  = out_ls + NTOT;        // (B,K,N,1)

    unsigned* ticket = (unsigned*)d_ws;
    u64* flags = (u64*)((char*)d_ws + 128);          // cacheline-separated

    // d_ws is poisoned to 0xAA each replay (0xAA.. has flag bits = PREFIX!) -> must zero.
    hipMemsetAsync(d_ws, 0, 128 + (size_t)NBLK * 8, stream);

    fused_expand<<<NBLK, 256, 0, stream>>>(rgb, lsurf, lair, idle, ms, ma,
                                           rgb_max, ts_max, ta_max,
                                           ticket, flags, out_rgb, out_ls, out_la);
}

// Round 4
// 161.315 us; speedup vs baseline: 2.4964x; 2.4964x over previous
//
#include <hip/hip_runtime.h>
#include <stdint.h>

// Problem constants (B=8, K=4, N=131072)
#define NPER      131072      // N = 2^17
#define NTOT      4194304LL   // B*K*N
#define CHUNK     2048        // elements per block
#define NBLK      2048        // NTOT / CHUNK
#define NEG_PAD   (-1000.0f)
#define NEG_IDLE  (-100000000.0f)

typedef unsigned long long u64;

// ---------------------------------------------------------------------------
// K1: read masks ONCE; emit (a) per-thread compressed 8+8 bit masks (u16),
// (b) per-block packed totals (surface | air<<32).
// Kernel boundary gives device-scope release/acquire -> K2 sees everything.
// ---------------------------------------------------------------------------
__global__ __launch_bounds__(256, 8) void count_kernel(
    const int* __restrict__ ms, const int* __restrict__ ma,
    unsigned short* __restrict__ cmp, u64* __restrict__ totals)
{
    const int t = threadIdx.x, lane = t & 63, wave = t >> 6;
    const unsigned bid = blockIdx.x;
    const long long base = (long long)bid * CHUNK;

    const int4* ms4 = (const int4*)(ms + base);
    const int4* ma4 = (const int4*)(ma + base);
    int4 s0 = ms4[2 * t], s1 = ms4[2 * t + 1];
    int4 a0 = ma4[2 * t], a1 = ma4[2 * t + 1];
    unsigned sbits = (unsigned)(s0.x != 0)        | ((unsigned)(s0.y != 0) << 1)
                   | ((unsigned)(s0.z != 0) << 2) | ((unsigned)(s0.w != 0) << 3)
                   | ((unsigned)(s1.x != 0) << 4) | ((unsigned)(s1.y != 0) << 5)
                   | ((unsigned)(s1.z != 0) << 6) | ((unsigned)(s1.w != 0) << 7);
    unsigned abits = (unsigned)(a0.x != 0)        | ((unsigned)(a0.y != 0) << 1)
                   | ((unsigned)(a0.z != 0) << 2) | ((unsigned)(a0.w != 0) << 3)
                   | ((unsigned)(a1.x != 0) << 4) | ((unsigned)(a1.y != 0) << 5)
                   | ((unsigned)(a1.z != 0) << 6) | ((unsigned)(a1.w != 0) << 7);

    cmp[bid * 256u + (unsigned)t] = (unsigned short)(sbits | (abits << 8));

    unsigned cnt = __popc(sbits) | (__popc(abits) << 16);   // block total <=2048/field
    #pragma unroll
    for (int o = 32; o; o >>= 1) cnt += __shfl_down(cnt, o, 64);
    __shared__ unsigned lds[4];
    if (lane == 0) lds[wave] = cnt;
    __syncthreads();
    if (t == 0) {
        unsigned tot = lds[0] + lds[1] + lds[2] + lds[3];
        totals[bid] = (u64)(tot & 0xffffu) | ((u64)(tot >> 16) << 32);
    }
}

// ---------------------------------------------------------------------------
// K2: exclusive prefix = predicated sum of totals[0..bid-1] (16 KB array,
// hot in L2/LLC). Per-lane bits from the 1 MB compressed array. Then expand
// and write with full coalescing. Gather index clipped per _expand's clip.
// ---------------------------------------------------------------------------
__global__ __launch_bounds__(256, 8) void expand_kernel(
    const float* __restrict__ rgb, const float* __restrict__ lsurf,
    const float* __restrict__ lair, const float* __restrict__ idle,
    const unsigned short* __restrict__ cmp, const u64* __restrict__ totals,
    unsigned rgb_max, unsigned ts_max, unsigned ta_max,
    float* __restrict__ out_rgb, float* __restrict__ out_ls, float* __restrict__ out_la)
{
    __shared__ unsigned wsum[4];
    __shared__ u64 wacc[4];
    const int t = threadIdx.x, lane = t & 63, wave = t >> 6;
    const unsigned bid = blockIdx.x;
    const long long base = (long long)bid * CHUNK;

    // --- issue independent loads early ---
    unsigned pk = cmp[bid * 256u + (unsigned)t];
    u64 acc = 0;
    #pragma unroll
    for (int j = 0; j < 8; ++j) {
        unsigned idx = (unsigned)t * 8u + (unsigned)j;
        acc += (idx < bid) ? totals[idx] : 0ULL;
    }
    const int bk = (int)(base >> 17);              // chunk lies in one (b,k) row
    const float idle_v = idle[bk];

    unsigned sbits = pk & 0xffu, abits = pk >> 8;
    unsigned cnt = __popc(sbits) | (__popc(abits) << 16);

    // --- block scan of per-thread counts (packed, no cross-field carry) ---
    unsigned x = cnt;
    #pragma unroll
    for (int o = 1; o < 64; o <<= 1) {
        unsigned y = __shfl_up(x, o, 64);
        if (lane >= o) x += y;
    }
    if (lane == 63) wsum[wave] = x;

    // --- reduce the predicated totals sum across the block ---
    #pragma unroll
    for (int o = 32; o; o >>= 1) acc += __shfl_down(acc, o, 64);
    if (lane == 0) wacc[wave] = acc;
    __syncthreads();
    unsigned w0 = wsum[0], w1 = wsum[1], w2 = wsum[2], w3 = wsum[3];
    unsigned pre   = (wave > 0 ? w0 : 0u) + (wave > 1 ? w1 : 0u) + (wave > 2 ? w2 : 0u);
    unsigned tExcl = pre + x - cnt;                // packed per-thread exclusive
    u64 basesum = wacc[0] + wacc[1] + wacc[2] + wacc[3];
    unsigned excS = (unsigned)(basesum & 0xffffffffULL);
    unsigned excA = (unsigned)(basesum >> 32);

    // --- expand + write: each thread owns 8 consecutive elements ---
    const float alive     = 1.0f - idle_v;
    const float idle_term = idle_v * NEG_IDLE;
    unsigned rs = excS + (tExcl & 0xffffu);
    unsigned ra = excA + (tExcl >> 16);
    const long long e0 = base + 8LL * t;

    float ls_b[8]  __attribute__((aligned(16)));
    float la_b[8]  __attribute__((aligned(16)));
    float rg_b[24] __attribute__((aligned(16)));
    #pragma unroll
    for (int j = 0; j < 8; ++j) {
        if ((sbits >> j) & 1u) {
            unsigned pr = rs < rgb_max ? rs : rgb_max;   // _expand's clip
            long long q = 3LL * pr;
            rg_b[3 * j]     = rgb[q]     * alive;
            rg_b[3 * j + 1] = rgb[q + 1] * alive;
            rg_b[3 * j + 2] = rgb[q + 2] * alive;
            unsigned pl = rs < ts_max ? rs : ts_max;
            ls_b[j] = lsurf[pl] * alive + idle_term;
            rs++;
        } else {
            rg_b[3 * j] = 0.f; rg_b[3 * j + 1] = 0.f; rg_b[3 * j + 2] = 0.f;
            ls_b[j] = NEG_PAD;
        }
        if ((abits >> j) & 1u) {
            unsigned pa = ra < ta_max ? ra : ta_max;
            la_b[j] = lair[pa] * alive + idle_term;
            ra++;
        } else {
            la_b[j] = NEG_PAD;
        }
    }

    float4* ols = (float4*)(out_ls + e0);
    ols[0] = ((float4*)ls_b)[0]; ols[1] = ((float4*)ls_b)[1];
    float4* ola = (float4*)(out_la + e0);
    ola[0] = ((float4*)la_b)[0]; ola[1] = ((float4*)la_b)[1];
    float4* org = (float4*)(out_rgb + 3 * e0);
    #pragma unroll
    for (int q = 0; q < 6; ++q) org[q] = ((float4*)rg_b)[q];
}

extern "C" void kernel_launch(void* const* d_in, const int* in_sizes, int n_in,
                              void* d_out, int out_size, void* d_ws, size_t ws_size,
                              hipStream_t stream)
{
    const float* rgb   = (const float*)d_in[0];
    const float* lsurf = (const float*)d_in[1];
    const float* lair  = (const float*)d_in[2];
    const float* idle  = (const float*)d_in[3];
    const int*   ms    = (const int*)d_in[4];   // bool -> int32 per harness contract
    const int*   ma    = (const int*)d_in[5];

    unsigned rgb_max = (unsigned)(in_sizes[0] / 3 - 1);
    unsigned ts_max  = (unsigned)(in_sizes[1] - 1);
    unsigned ta_max  = (unsigned)(in_sizes[2] - 1);

    float* out     = (float*)d_out;
    float* out_rgb = out;                  // (B,K,N,3)
    float* out_ls  = out + NTOT * 3;       // (B,K,N,1)
    float* out_la  = out_ls + NTOT;        // (B,K,N,1)

    // Workspace: totals (2048 * 8 B = 16 KB) then compressed masks (1 MB).
    // Both fully rewritten by K1 every launch -> no init needed despite poison.
    u64* totals = (u64*)d_ws;
    unsigned short* cmp = (unsigned short*)((char*)d_ws + 16384);

    count_kernel<<<NBLK, 256, 0, stream>>>(ms, ma, cmp, totals);
    expand_kernel<<<NBLK, 256, 0, stream>>>(rgb, lsurf, lair, idle, cmp, totals,
                                            rgb_max, ts_max, ta_max,
                                            out_rgb, out_ls, out_la);
}

// Round 5
// 148.883 us; speedup vs baseline: 2.7049x; 1.0835x over previous
//
#include <hip/hip_runtime.h>
#include <stdint.h>

// Problem constants (B=8, K=4, N=131072)
#define NPER      131072      // N = 2^17
#define NTOT      4194304LL   // B*K*N
#define CHUNK     2048        // elements per block
#define NBLK      2048        // NTOT / CHUNK
#define NEG_PAD   (-1000.0f)
#define NEG_IDLE  (-100000000.0f)

typedef unsigned long long u64;

// ---------------------------------------------------------------------------
// K1: read masks ONCE (int32 bools); emit per-8-element compressed bitmasks
// (u16: sbits | abits<<8) and per-block packed totals (surface | air<<32).
// ---------------------------------------------------------------------------
__global__ __launch_bounds__(256, 8) void count_kernel(
    const int* __restrict__ ms, const int* __restrict__ ma,
    unsigned short* __restrict__ cmp, u64* __restrict__ totals)
{
    const int t = threadIdx.x, lane = t & 63, wave = t >> 6;
    const unsigned bid = blockIdx.x;
    const long long base = (long long)bid * CHUNK;

    const int4* ms4 = (const int4*)(ms + base);
    const int4* ma4 = (const int4*)(ma + base);
    int4 s0 = ms4[2 * t], s1 = ms4[2 * t + 1];
    int4 a0 = ma4[2 * t], a1 = ma4[2 * t + 1];
    unsigned sbits = (unsigned)(s0.x != 0)        | ((unsigned)(s0.y != 0) << 1)
                   | ((unsigned)(s0.z != 0) << 2) | ((unsigned)(s0.w != 0) << 3)
                   | ((unsigned)(s1.x != 0) << 4) | ((unsigned)(s1.y != 0) << 5)
                   | ((unsigned)(s1.z != 0) << 6) | ((unsigned)(s1.w != 0) << 7);
    unsigned abits = (unsigned)(a0.x != 0)        | ((unsigned)(a0.y != 0) << 1)
                   | ((unsigned)(a0.z != 0) << 2) | ((unsigned)(a0.w != 0) << 3)
                   | ((unsigned)(a1.x != 0) << 4) | ((unsigned)(a1.y != 0) << 5)
                   | ((unsigned)(a1.z != 0) << 6) | ((unsigned)(a1.w != 0) << 7);

    cmp[bid * 256u + (unsigned)t] = (unsigned short)(sbits | (abits << 8));

    unsigned cnt = __popc(sbits) | (__popc(abits) << 16);   // block total <=2048/field
    #pragma unroll
    for (int o = 32; o; o >>= 1) cnt += __shfl_down(cnt, o, 64);
    __shared__ unsigned lds[4];
    if (lane == 0) lds[wave] = cnt;
    __syncthreads();
    if (t == 0) {
        unsigned tot = lds[0] + lds[1] + lds[2] + lds[3];
        totals[bid] = (u64)(tot & 0xffffu) | ((u64)(tot >> 16) << 32);
    }
}

// ---------------------------------------------------------------------------
// K2: per-pack prefixes via ONE block scan (stored in LDS); block-exclusive
// base from predicated sum of the 16 KB totals array. Then 8 rounds where
// lane t owns element r*256+t: rank = pref[pack] + popc(low bits). ls/la
// stores are lane-consecutive dwords (coalesced); rgb staged in a 12 KB LDS
// tile per 4 rounds, bulk-copied as lane-consecutive float4s (coalesced).
// ---------------------------------------------------------------------------
__global__ __launch_bounds__(256, 8) void expand_kernel(
    const float* __restrict__ rgb, const float* __restrict__ lsurf,
    const float* __restrict__ lair, const float* __restrict__ idle,
    const unsigned short* __restrict__ cmp, const u64* __restrict__ totals,
    unsigned rgb_max, unsigned ts_max, unsigned ta_max,
    float* __restrict__ out_rgb, float* __restrict__ out_ls, float* __restrict__ out_la)
{
    __shared__ unsigned wsum[4];
    __shared__ u64 wacc[4];
    __shared__ unsigned packLDS[256];   // u16 pack per 8 elements
    __shared__ unsigned prefLDS[256];   // packed exclusive prefix (s | a<<16)
    __shared__ float    rgbLDS[3072];   // 12 KB: 4 rounds of 256*3 floats

    const int t = threadIdx.x, lane = t & 63, wave = t >> 6;
    const unsigned bid = blockIdx.x;
    const long long base = (long long)bid * CHUNK;

    // --- independent loads first ---
    unsigned pk = cmp[bid * 256u + (unsigned)t];
    u64 acc = 0;
    #pragma unroll
    for (int j = 0; j < 8; ++j) {
        unsigned idx = (unsigned)t * 8u + (unsigned)j;
        acc += (idx < bid) ? totals[idx] : 0ULL;
    }
    const float idle_v = idle[(int)(base >> 17)];     // chunk lies in one (b,k) row

    packLDS[t] = pk;
    unsigned cnt = __popc(pk & 0xffu) | (__popc(pk >> 8) << 16);

    // --- one block scan over per-pack counts (packed, no cross-field carry) ---
    unsigned x = cnt;
    #pragma unroll
    for (int o = 1; o < 64; o <<= 1) {
        unsigned y = __shfl_up(x, o, 64);
        if (lane >= o) x += y;
    }
    if (lane == 63) wsum[wave] = x;
    #pragma unroll
    for (int o = 32; o; o >>= 1) acc += __shfl_down(acc, o, 64);
    if (lane == 0) wacc[wave] = acc;
    __syncthreads();
    unsigned pre = (wave > 0 ? wsum[0] : 0u) + (wave > 1 ? wsum[1] : 0u)
                 + (wave > 2 ? wsum[2] : 0u);
    prefLDS[t] = pre + x - cnt;                       // per-pack exclusive (packed)
    u64 basesum = wacc[0] + wacc[1] + wacc[2] + wacc[3];
    const unsigned excS = (unsigned)(basesum & 0xffffffffULL);
    const unsigned excA = (unsigned)(basesum >> 32);
    __syncthreads();                                  // prefLDS/packLDS visible

    const float alive     = 1.0f - idle_v;
    const float idle_term = idle_v * NEG_IDLE;
    const int  sub = t >> 3, b = t & 7;
    const unsigned sm = (1u << b) - 1u;

    #pragma unroll
    for (int h = 0; h < 2; ++h) {
        #pragma unroll
        for (int r = 0; r < 4; ++r) {
            const int e = (h * 4 + r) * 256 + t;      // element within block
            const int p = ((h * 4 + r) << 5) + sub;   // pack index
            unsigned w  = packLDS[p];
            unsigned pv = prefLDS[p];
            unsigned rs = excS + (pv & 0xffffu) + __popc(w & sm);
            unsigned ra = excA + (pv >> 16)     + __popc((w >> 8) & sm);
            unsigned s = (w >> b) & 1u, a = (w >> (8 + b)) & 1u;

            float lso = NEG_PAD, lao = NEG_PAD;
            const int li = r * 768 + 3 * t;           // LDS dword offset (bank: 3t%32, 2-way free)
            if (s) {
                unsigned pr = rs < rgb_max ? rs : rgb_max;   // _expand's clip
                long long q = 3LL * pr;
                rgbLDS[li]     = rgb[q]     * alive;
                rgbLDS[li + 1] = rgb[q + 1] * alive;
                rgbLDS[li + 2] = rgb[q + 2] * alive;
                unsigned pl = rs < ts_max ? rs : ts_max;
                lso = lsurf[pl] * alive + idle_term;
            } else {
                rgbLDS[li] = 0.f; rgbLDS[li + 1] = 0.f; rgbLDS[li + 2] = 0.f;
            }
            if (a) {
                unsigned pa = ra < ta_max ? ra : ta_max;
                lao = lair[pa] * alive + idle_term;
            }
            out_ls[base + e] = lso;                   // lane-consecutive: coalesced
            out_la[base + e] = lao;
        }
        __syncthreads();                              // rgb tile complete
        // bulk copy 12 KB tile -> global, lane-consecutive float4 (coalesced)
        float4* dst = (float4*)(out_rgb + 3 * base) + (h ? 768 : 0);
        const float4* src = (const float4*)rgbLDS;
        dst[t]       = src[t];
        dst[t + 256] = src[t + 256];
        dst[t + 512] = src[t + 512];
        __syncthreads();                              // tile reusable
    }
}

extern "C" void kernel_launch(void* const* d_in, const int* in_sizes, int n_in,
                              void* d_out, int out_size, void* d_ws, size_t ws_size,
                              hipStream_t stream)
{
    const float* rgb   = (const float*)d_in[0];
    const float* lsurf = (const float*)d_in[1];
    const float* lair  = (const float*)d_in[2];
    const float* idle  = (const float*)d_in[3];
    const int*   ms    = (const int*)d_in[4];   // bool -> int32 per harness contract
    const int*   ma    = (const int*)d_in[5];

    unsigned rgb_max = (unsigned)(in_sizes[0] / 3 - 1);
    unsigned ts_max  = (unsigned)(in_sizes[1] - 1);
    unsigned ta_max  = (unsigned)(in_sizes[2] - 1);

    float* out     = (float*)d_out;
    float* out_rgb = out;                  // (B,K,N,3)
    float* out_ls  = out + NTOT * 3;       // (B,K,N,1)
    float* out_la  = out_ls + NTOT;        // (B,K,N,1)

    // Workspace: totals (2048 * 8 B = 16 KB) then compressed masks (1 MB).
    // Both fully rewritten by K1 every launch -> no init needed despite poison.
    u64* totals = (u64*)d_ws;
    unsigned short* cmp = (unsigned short*)((char*)d_ws + 16384);

    count_kernel<<<NBLK, 256, 0, stream>>>(ms, ma, cmp, totals);
    expand_kernel<<<NBLK, 256, 0, stream>>>(rgb, lsurf, lair, idle, cmp, totals,
                                            rgb_max, ts_max, ta_max,
                                            out_rgb, out_ls, out_la);
}

// Round 6
// 147.853 us; speedup vs baseline: 2.7237x; 1.0070x over previous
//
#include <hip/hip_runtime.h>
#include <stdint.h>

// Problem constants (B=8, K=4, N=131072)
#define NTOT      4194304LL   // B*K*N
#define CHUNK     2048        // elements per block
#define NBLK      2048        // NTOT / CHUNK
#define NEG_PAD   (-1000.0f)
#define NEG_IDLE  (-100000000.0f)

typedef unsigned long long u64;
typedef float float4u __attribute__((ext_vector_type(4), aligned(4)));   // dwordx4, 4-B align
typedef float float3u __attribute__((ext_vector_type(3), aligned(4)));   // dwordx3, loads 12 B
typedef float float4a __attribute__((ext_vector_type(4), aligned(16)));

// ---------------------------------------------------------------------------
// K1: read masks ONCE (int32 bools); emit per-8-element compressed bitmasks
// (u16: sbits | abits<<8) and per-block packed totals (surface | air<<32).
// ---------------------------------------------------------------------------
__global__ __launch_bounds__(256, 8) void count_kernel(
    const int* __restrict__ ms, const int* __restrict__ ma,
    unsigned short* __restrict__ cmp, u64* __restrict__ totals)
{
    const int t = threadIdx.x, lane = t & 63, wave = t >> 6;
    const unsigned bid = blockIdx.x;
    const long long base = (long long)bid * CHUNK;

    const int4* ms4 = (const int4*)(ms + base);
    const int4* ma4 = (const int4*)(ma + base);
    int4 s0 = ms4[2 * t], s1 = ms4[2 * t + 1];
    int4 a0 = ma4[2 * t], a1 = ma4[2 * t + 1];
    unsigned sbits = (unsigned)(s0.x != 0)        | ((unsigned)(s0.y != 0) << 1)
                   | ((unsigned)(s0.z != 0) << 2) | ((unsigned)(s0.w != 0) << 3)
                   | ((unsigned)(s1.x != 0) << 4) | ((unsigned)(s1.y != 0) << 5)
                   | ((unsigned)(s1.z != 0) << 6) | ((unsigned)(s1.w != 0) << 7);
    unsigned abits = (unsigned)(a0.x != 0)        | ((unsigned)(a0.y != 0) << 1)
                   | ((unsigned)(a0.z != 0) << 2) | ((unsigned)(a0.w != 0) << 3)
                   | ((unsigned)(a1.x != 0) << 4) | ((unsigned)(a1.y != 0) << 5)
                   | ((unsigned)(a1.z != 0) << 6) | ((unsigned)(a1.w != 0) << 7);

    cmp[bid * 256u + (unsigned)t] = (unsigned short)(sbits | (abits << 8));

    unsigned cnt = __popc(sbits) | (__popc(abits) << 16);
    #pragma unroll
    for (int o = 32; o; o >>= 1) cnt += __shfl_down(cnt, o, 64);
    __shared__ unsigned lds[4];
    if (lane == 0) lds[wave] = cnt;
    __syncthreads();
    if (t == 0) {
        unsigned tot = lds[0] + lds[1] + lds[2] + lds[3];
        totals[bid] = (u64)(tot & 0xffffu) | ((u64)(tot >> 16) << 32);
    }
}

// ---------------------------------------------------------------------------
// K2: per-pack prefixes via one block scan; block base via predicated sum of
// the 16 KB totals array (L2-hot). rgb: per-element dwordx3 gathers into a
// 12 KB LDS tile, bulk-copied as coalesced float4. ls/la: each thread owns 4
// consecutive elements; ONE dwordx4 window gather covers all its active
// ranks (consecutive), values selected in-register; float4 coalesced stores.
// ---------------------------------------------------------------------------
__global__ __launch_bounds__(256, 6) void expand_kernel(
    const float* __restrict__ rgb, const float* __restrict__ lsurf,
    const float* __restrict__ lair, const float* __restrict__ idle,
    const unsigned short* __restrict__ cmp, const u64* __restrict__ totals,
    unsigned rgb_max, unsigned ts_max, unsigned ta_max,
    float* __restrict__ out_rgb, float* __restrict__ out_ls, float* __restrict__ out_la)
{
    __shared__ unsigned wsum[4];
    __shared__ u64 wacc[4];
    __shared__ unsigned packLDS[256];   // u16 pack per 8 elements
    __shared__ unsigned prefLDS[256];   // packed exclusive prefix (s | a<<16)
    __shared__ float    rgbLDS[3072];   // 12 KB: 4 rounds of 256*3 floats

    const int t = threadIdx.x, lane = t & 63, wave = t >> 6;
    const unsigned bid = blockIdx.x;
    const long long base = (long long)bid * CHUNK;

    // --- independent loads first ---
    unsigned pk = cmp[bid * 256u + (unsigned)t];
    u64 acc = 0;
    #pragma unroll
    for (int j = 0; j < 8; ++j) {
        unsigned idx = (unsigned)t * 8u + (unsigned)j;
        acc += (idx < bid) ? totals[idx] : 0ULL;
    }
    const float idle_v = idle[(int)(base >> 17)];     // chunk lies in one (b,k) row

    packLDS[t] = pk;
    unsigned cnt = __popc(pk & 0xffu) | (__popc(pk >> 8) << 16);

    unsigned x = cnt;
    #pragma unroll
    for (int o = 1; o < 64; o <<= 1) {
        unsigned y = __shfl_up(x, o, 64);
        if (lane >= o) x += y;
    }
    if (lane == 63) wsum[wave] = x;
    #pragma unroll
    for (int o = 32; o; o >>= 1) acc += __shfl_down(acc, o, 64);
    if (lane == 0) wacc[wave] = acc;
    __syncthreads();
    unsigned pre = (wave > 0 ? wsum[0] : 0u) + (wave > 1 ? wsum[1] : 0u)
                 + (wave > 2 ? wsum[2] : 0u);
    prefLDS[t] = pre + x - cnt;                       // per-pack exclusive (packed)
    u64 basesum = wacc[0] + wacc[1] + wacc[2] + wacc[3];
    const unsigned excS = (unsigned)(basesum & 0xffffffffULL);
    const unsigned excA = (unsigned)(basesum >> 32);
    __syncthreads();

    const float alive     = 1.0f - idle_v;
    const float idle_term = idle_v * NEG_IDLE;
    const int  sub = t >> 3, b = t & 7;
    const unsigned bm = (1u << b) - 1u;
    const int  hp = t >> 1;                // pack within half for ls/la ownership
    const unsigned nib = (unsigned)(t & 1) * 4u;
    const unsigned nm  = (1u << nib) - 1u;

    #pragma unroll
    for (int h = 0; h < 2; ++h) {
        // ---- rgb: 4 rounds of 256, one dwordx3 gather each, into LDS tile ----
        #pragma unroll
        for (int r = 0; r < 4; ++r) {
            const int g = h * 4 + r;
            const int p = (g << 5) + sub;
            unsigned w  = packLDS[p];
            unsigned pv = prefLDS[p];
            unsigned rs = excS + (pv & 0xffffu) + __popc(w & bm);
            const int li = r * 768 + 3 * t;           // banks 3t%32: 2-way, free
            if ((w >> b) & 1u) {
                unsigned pr = rs < rgb_max ? rs : rgb_max;   // _expand's clip
                float3u v = *(const float3u*)(rgb + 3LL * pr);
                rgbLDS[li]     = v.x * alive;
                rgbLDS[li + 1] = v.y * alive;
                rgbLDS[li + 2] = v.z * alive;
            } else {
                rgbLDS[li] = 0.f; rgbLDS[li + 1] = 0.f; rgbLDS[li + 2] = 0.f;
            }
        }
        // ---- ls/la: 4 consecutive elements, window gather + select ----
        {
            const int p = h * 128 + hp;
            unsigned w  = packLDS[p];
            unsigned pv = prefLDS[p];
            unsigned ws = w & 0xffu, wa = (w >> 8) & 0xffu;
            unsigned r0s = excS + (pv & 0xffffu) + __popc(ws & nm);
            unsigned r0a = excA + (pv >> 16)     + __popc(wa & nm);
            unsigned sb = (ws >> nib) & 0xFu;
            unsigned ab = (wa >> nib) & 0xFu;
            unsigned rbs = r0s < ts_max - 3u ? r0s : ts_max - 3u;
            unsigned rba = r0a < ta_max - 3u ? r0a : ta_max - 3u;
            float4u Ws = *(const float4u*)(lsurf + rbs);   // covers ranks rbs..rbs+3
            float4u Wa = *(const float4u*)(lair  + rba);
            float lsv[4], lav[4];
            #pragma unroll
            for (int j = 0; j < 4; ++j) {
                unsigned mj = (1u << j) - 1u;
                unsigned rj = r0s + __popc(sb & mj);
                unsigned cs = (rj < ts_max ? rj : ts_max) - rbs;   // 0..3
                float vs = cs == 0 ? Ws.x : cs == 1 ? Ws.y : cs == 2 ? Ws.z : Ws.w;
                lsv[j] = ((sb >> j) & 1u) ? vs * alive + idle_term : NEG_PAD;
                unsigned rk = r0a + __popc(ab & mj);
                unsigned ca = (rk < ta_max ? rk : ta_max) - rba;
                float va = ca == 0 ? Wa.x : ca == 1 ? Wa.y : ca == 2 ? Wa.z : Wa.w;
                lav[j] = ((ab >> j) & 1u) ? va * alive + idle_term : NEG_PAD;
            }
            const long long eb = base + h * 1024 + 4 * t;  // 16-B aligned
            float4a vls; vls.x = lsv[0]; vls.y = lsv[1]; vls.z = lsv[2]; vls.w = lsv[3];
            float4a vla; vla.x = lav[0]; vla.y = lav[1]; vla.z = lav[2]; vla.w = lav[3];
            *(float4a*)(out_ls + eb) = vls;
            *(float4a*)(out_la + eb) = vla;
        }
        __syncthreads();                              // rgb tile complete
        float4a* dst = (float4a*)(out_rgb + 3 * base) + h * 768;
        const float4a* src = (const float4a*)rgbLDS;
        dst[t]       = src[t];
        dst[t + 256] = src[t + 256];
        dst[t + 512] = src[t + 512];
        __syncthreads();                              // tile reusable
    }
}

extern "C" void kernel_launch(void* const* d_in, const int* in_sizes, int n_in,
                              void* d_out, int out_size, void* d_ws, size_t ws_size,
                              hipStream_t stream)
{
    const float* rgb   = (const float*)d_in[0];
    const float* lsurf = (const float*)d_in[1];
    const float* lair  = (const float*)d_in[2];
    const float* idle  = (const float*)d_in[3];
    const int*   ms    = (const int*)d_in[4];   // bool -> int32 per harness contract
    const int*   ma    = (const int*)d_in[5];

    unsigned rgb_max = (unsigned)(in_sizes[0] / 3 - 1);
    unsigned ts_max  = (unsigned)(in_sizes[1] - 1);
    unsigned ta_max  = (unsigned)(in_sizes[2] - 1);

    float* out     = (float*)d_out;
    float* out_rgb = out;                  // (B,K,N,3)
    float* out_ls  = out + NTOT * 3;       // (B,K,N,1)
    float* out_la  = out_ls + NTOT;        // (B,K,N,1)

    // Workspace: totals (16 KB) then compressed masks (1 MB); both fully
    // rewritten by K1 every launch -> no init needed despite 0xAA poison.
    u64* totals = (u64*)d_ws;
    unsigned short* cmp = (unsigned short*)((char*)d_ws + 16384);

    count_kernel<<<NBLK, 256, 0, stream>>>(ms, ma, cmp, totals);
    expand_kernel<<<NBLK, 256, 0, stream>>>(rgb, lsurf, lair, idle, cmp, totals,
                                            rgb_max, ts_max, ta_max,
                                            out_rgb, out_ls, out_la);
}